// Round 6
// baseline (241.907 us; speedup 1.0000x reference)
//
#include <hip/hip_runtime.h>
#include <math.h>

#define CH 512
#define RED 64

typedef __attribute__((ext_vector_type(4))) float f32x4;
typedef long i64;

typedef const __attribute__((address_space(1))) void* gas_t;
typedef __attribute__((address_space(3))) void* las_t;

static __device__ __forceinline__ void gl16(const void* g, void* l) {
    __builtin_amdgcn_global_load_lds((gas_t)g, (las_t)l, 16, 0, 0);
}

// pack f32 -> fp8 e4m3
static __device__ __forceinline__ unsigned pk4(float a, float b, float c, float d) {
    int w = __builtin_amdgcn_cvt_pk_fp8_f32(a, b, 0, false);
    w = __builtin_amdgcn_cvt_pk_fp8_f32(c, d, w, true);
    return (unsigned)w;
}
static __device__ __forceinline__ unsigned char pk1(float a) {
    return (unsigned char)(__builtin_amdgcn_cvt_pk_fp8_f32(a, a, 0, false) & 0xFF);
}

// hardware exp2 (v_exp_f32 IS base-2)
static __device__ __forceinline__ float fexp2(float v) {
#if __has_builtin(__builtin_amdgcn_exp2f)
    return __builtin_amdgcn_exp2f(v);
#else
    float r; asm("v_exp_f32 %0, %1" : "=v"(r) : "v"(v)); return r;
#endif
}

// raw workgroup barrier with compiler memory fences (no implicit vmcnt(0) drain)
static __device__ __forceinline__ void barrier_raw() {
    asm volatile("" ::: "memory");
    __builtin_amdgcn_s_barrier();
    asm volatile("" ::: "memory");
}

// ---------------------------------------------------------------------------
// prep_w: Wq|Wk|Wv f32 -> Wcat fp8 [640][512]; rows 0-63 q, 64-127 k, 128-639 v.
// ---------------------------------------------------------------------------
__global__ __launch_bounds__(128) void prep_w(
    const float* __restrict__ Wq, const float* __restrict__ Wk,
    const float* __restrict__ Wv, unsigned char* __restrict__ Wcat)
{
    const int r = blockIdx.x, t = threadIdx.x;
    const float* src = (r < 64) ? (Wq + (size_t)r * CH)
                     : (r < 128) ? (Wk + (size_t)(r - 64) * CH)
                                 : (Wv + (size_t)(r - 128) * CH);
    const float4 v = *(const float4*)&src[t * 4];
    *(unsigned*)&Wcat[(size_t)r * CH + t * 4] = pk4(v.x, v.y, v.z, v.w);
}

// ---------------------------------------------------------------------------
// cast_xt: x f32 [b][c][n] -> xT fp8 [b][n][512].  64x64 tiles.
// ---------------------------------------------------------------------------
__global__ __launch_bounds__(256) void cast_xt(
    const float* __restrict__ x, unsigned char* __restrict__ xT, int n)
{
    __shared__ float sX[64][65];
    const int b = blockIdx.z, i0 = blockIdx.x * 64, c0 = blockIdx.y * 64;
    const int t = threadIdx.x;
    #pragma unroll
    for (int s = 0; s < 4; ++s) {
        const int id = s * 256 + t, c = id >> 4, seg = id & 15;
        *(float4*)&sX[c][seg * 4] = *(const float4*)&x[((size_t)b * CH + c0 + c) * n + i0 + seg * 4];
    }
    __syncthreads();
    const int i = t >> 2, cp = t & 3;
    uint4 w;
    w.x = pk4(sX[cp*16+ 0][i], sX[cp*16+ 1][i], sX[cp*16+ 2][i], sX[cp*16+ 3][i]);
    w.y = pk4(sX[cp*16+ 4][i], sX[cp*16+ 5][i], sX[cp*16+ 6][i], sX[cp*16+ 7][i]);
    w.z = pk4(sX[cp*16+ 8][i], sX[cp*16+ 9][i], sX[cp*16+10][i], sX[cp*16+11][i]);
    w.w = pk4(sX[cp*16+12][i], sX[cp*16+13][i], sX[cp*16+14][i], sX[cp*16+15][i]);
    *(uint4*)&xT[((size_t)b * n + i0 + i) * CH + c0 + cp * 16] = w;
}

// ---------------------------------------------------------------------------
// qkv_gemm (fp8): out = xT * Wcat^T + bias.  128i x 128o tiles, K=512.
// q-rows scaled by log2(e) before fp8 quantization -> attn softmax is a
// single v_exp_f32 (exp2 domain).
// ---------------------------------------------------------------------------
__global__ __launch_bounds__(256, 4) void qkv_gemm(
    const unsigned char* __restrict__ xT, const unsigned char* __restrict__ Wcat,
    const float* __restrict__ bq, const float* __restrict__ bk,
    const float* __restrict__ bv,
    unsigned char* __restrict__ qF, unsigned char* __restrict__ kF,
    unsigned char* __restrict__ v2, int n)
{
    __shared__ char smem[20480];   // sA 128x80 | sB 128x80
    const int b = blockIdx.z, i0 = blockIdx.x * 128, o0 = blockIdx.y * 128;
    const int t = threadIdx.x, lane = t & 63;
    const int quad = lane >> 4, l16 = lane & 15;
    const int wrow = (t >> 6) & 1, wcol = t >> 7;

    f32x4 acc[4][4];
    const f32x4 zz = {0.f, 0.f, 0.f, 0.f};
    #pragma unroll
    for (int mi = 0; mi < 4; ++mi)
        #pragma unroll
        for (int ci = 0; ci < 4; ++ci) acc[mi][ci] = zz;

    const unsigned char* Ab = xT + ((size_t)b * n + i0) * CH;
    const unsigned char* Bb = Wcat + (size_t)o0 * CH;

    for (int c0 = 0; c0 < CH; c0 += 64) {
        #pragma unroll
        for (int s = 0; s < 5; ++s) {
            const int c = s * 256 + t;
            const bool isA = c < 640;
            const int tc = isA ? c : c - 640;
            const int r = tc / 5, p = (tc % 5) & 3;
            gl16((isA ? Ab : Bb) + (size_t)r * CH + c0 + p * 16,
                 smem + (isA ? 0 : 10240) + (size_t)tc * 16);
        }
        __syncthreads();
        #pragma unroll
        for (int kk = 0; kk < 64; kk += 32) {
            i64 af[4], bf[4];
            #pragma unroll
            for (int mi = 0; mi < 4; ++mi)
                af[mi] = *(const i64*)(smem + (wrow * 64 + mi * 16 + l16) * 80 + kk + quad * 8);
            #pragma unroll
            for (int ci = 0; ci < 4; ++ci)
                bf[ci] = *(const i64*)(smem + 10240 + (wcol * 64 + ci * 16 + l16) * 80 + kk + quad * 8);
            #pragma unroll
            for (int mi = 0; mi < 4; ++mi)
                #pragma unroll
                for (int ci = 0; ci < 4; ++ci)
                    acc[mi][ci] = __builtin_amdgcn_mfma_f32_16x16x32_fp8_fp8(af[mi], bf[ci], acc[mi][ci], 0, 0, 0);
        }
        __syncthreads();
    }

    float bb[4], scl[4];
    #pragma unroll
    for (int ci = 0; ci < 4; ++ci) {
        const int o = wcol * 64 + ci * 16 + l16;
        if (o0 == 0) {
            bb[ci]  = (o < 64) ? bq[o] : bk[o - 64];
            scl[ci] = (o < 64) ? 1.44269504088896f : 1.0f;
        } else {
            bb[ci]  = bv[o0 - 128 + o];
            scl[ci] = 1.0f;
        }
    }
    __syncthreads();
    unsigned char* sE = (unsigned char*)smem;    // 128 x 144
    if (o0 == 0) {
        #pragma unroll
        for (int mi = 0; mi < 4; ++mi)
            #pragma unroll
            for (int ci = 0; ci < 4; ++ci)
                #pragma unroll
                for (int r = 0; r < 4; ++r)
                    sE[(wrow*64 + mi*16 + quad*4 + r) * 144 + wcol*64 + ci*16 + l16] =
                        pk1((acc[mi][ci][r] + bb[ci]) * scl[ci]);
    } else {
        #pragma unroll
        for (int mi = 0; mi < 4; ++mi)
            #pragma unroll
            for (int ci = 0; ci < 4; ++ci)
                #pragma unroll
                for (int r = 0; r < 4; ++r)
                    sE[(wcol*64 + ci*16 + l16) * 144 + wrow*64 + mi*16 + quad*4 + r] =
                        pk1(acc[mi][ci][r] + bb[ci]);
    }
    __syncthreads();
    if (o0 == 0) {
        #pragma unroll
        for (int u = 0; u < 2; ++u) {
            const int id = u * 256 + t, i = id >> 2, p = id & 3;
            *(uint4*)&qF[((size_t)b * n + i0 + i) * RED + p * 16] = *(const uint4*)&sE[i * 144 + p * 16];
        }
        #pragma unroll
        for (int u = 0; u < 2; ++u) {
            const int id = u * 256 + t, i = id >> 2, p = id & 3;
            *(uint4*)&kF[((size_t)b * n + i0 + i) * RED + p * 16] = *(const uint4*)&sE[i * 144 + 64 + p * 16];
        }
    } else {
        #pragma unroll
        for (int u = 0; u < 4; ++u) {
            const int id = u * 256 + t, o = id >> 3, p = id & 7;
            *(uint4*)&v2[((size_t)b * CH + (o0 - 128) + o) * n + i0 + p * 16] =
                *(const uint4*)&sE[o * 144 + p * 16];
        }
    }
}

// ---------------------------------------------------------------------------
// attn v8: v7 geometry + DEFER-MAX (T13).  Common path = 3 barriers/chunk
// (v5 structure) with SPECULATIVE P = exp2(S - m_old):
//   S -> [per-lane overflow check -> ballot -> flag write || quad-shfl max
//        -> sMx write || exp2/P write (speculative, esum held)] ->
//   lgkm+B2 -> read 8 flags (broadcast) ->
//     accept (flags==0): lacc += esum                       [no rescale]
//     redo   (rare):     m=max(m,union), recompute/rewrite P, rescale
//                        acc/lacc, extra lgkm+barrier
//   -> PV -> lgkm+B3 -> stage(c+2)+counted vmcnt+B1
// Safety: accept guaranteed P <= 2^THR = 16 << 448 (fp8 max); m_old only
// LAGS the true running max, so underflow <= exact flash.  Chunk 0 always
// redoes (m init -3e38; speculative garbage fully rewritten, lacc*0).
// ---------------------------------------------------------------------------
#define STGSZ 20480
#define SPOFF 40960
#define SLOFF 45056
#define FLGO  46080
#define THRV  4.0f

#define CHUNK(BASE, cc) do {                                                  \
    f32x4 S0 = zz, S1 = zz;                                                   \
    __builtin_amdgcn_s_setprio(1);                                            \
    {                                                                         \
        const i64 kf0 = *(const i64*)(smem + (BASE) + fA);                    \
        const i64 kf1 = *(const i64*)(smem + (BASE) + (fA ^ 32));             \
        S0 = __builtin_amdgcn_mfma_f32_16x16x32_fp8_fp8(kf0, qreg[0][0], S0, 0, 0, 0); \
        S1 = __builtin_amdgcn_mfma_f32_16x16x32_fp8_fp8(kf0, qreg[1][0], S1, 0, 0, 0); \
        S0 = __builtin_amdgcn_mfma_f32_16x16x32_fp8_fp8(kf1, qreg[0][1], S0, 0, 0, 0); \
        S1 = __builtin_amdgcn_mfma_f32_16x16x32_fp8_fp8(kf1, qreg[1][1], S1, 0, 0, 0); \
    }                                                                         \
    __builtin_amdgcn_s_setprio(0);                                            \
    /* per-lane 4-reg maxima: overflow detector + sMx union material */      \
    float c0 = fmaxf(fmaxf(S0[0], S0[1]), fmaxf(S0[2], S0[3]));               \
    float c1 = fmaxf(fmaxf(S1[0], S1[1]), fmaxf(S1[2], S1[3]));               \
    const bool predl = (c0 > mold[0] + THRV) || (c1 > mold[1] + THRV);        \
    const unsigned long long ball = __ballot(predl);                          \
    if (lane == 0) *(unsigned*)(smem + FLGO + w * 4) = (ball != 0ull) ? 1u : 0u; \
    c0 = fmaxf(c0, __shfl_xor(c0, 16)); c0 = fmaxf(c0, __shfl_xor(c0, 32));   \
    c1 = fmaxf(c1, __shfl_xor(c1, 16)); c1 = fmaxf(c1, __shfl_xor(c1, 32));   \
    if (quad == 0) {                                                          \
        *(float*)(smem + mxW) = c0;                                           \
        *(float*)(smem + mxW + 256) = c1;                                     \
    }                                                                         \
    /* speculative P with m_old (esum held in regs, not yet committed) */     \
    float es0, es1;                                                           \
    {                                                                         \
        const float e0 = fexp2(S0[0] - mold[0]), e1 = fexp2(S0[1] - mold[0]); \
        const float e2 = fexp2(S0[2] - mold[0]), e3 = fexp2(S0[3] - mold[0]); \
        es0 = (e0 + e1) + (e2 + e3);                                          \
        *(unsigned*)(smem + pwA) = pk4(e0, e1, e2, e3);                       \
        const float f0 = fexp2(S1[0] - mold[1]), f1 = fexp2(S1[1] - mold[1]); \
        const float f2 = fexp2(S1[2] - mold[1]), f3 = fexp2(S1[3] - mold[1]); \
        es1 = (f0 + f1) + (f2 + f3);                                          \
        *(unsigned*)(smem + pwA + 1024) = pk4(f0, f1, f2, f3);                \
    }                                                                         \
    asm volatile("s_waitcnt lgkmcnt(0)" ::: "memory");                        \
    barrier_raw();   /* B2: P + sMx + flags visible; staging in flight */     \
    const uint4 fw0 = *(const uint4*)(smem + FLGO);                           \
    const uint4 fw1 = *(const uint4*)(smem + FLGO + 16);                      \
    if (fw0.x | fw0.y | fw0.z | fw0.w | fw1.x | fw1.y | fw1.z | fw1.w) {      \
        /* ---- redo (rare): union max, recompute + rewrite P, rescale */     \
        const f32x4 mx0 = *(const f32x4*)(smem + mxR);                        \
        const f32x4 mx1 = *(const f32x4*)(smem + mxR + 256);                  \
        const float cd0 = fmaxf(fmaxf(mx0[0], mx0[1]), fmaxf(mx0[2], mx0[3]));\
        const float cd1 = fmaxf(fmaxf(mx1[0], mx1[1]), fmaxf(mx1[2], mx1[3]));\
        const float mn0 = fmaxf(mold[0], cd0), mn1 = fmaxf(mold[1], cd1);     \
        const float rs0 = fexp2(mold[0] - mn0), rs1 = fexp2(mold[1] - mn1);   \
        mold[0] = mn0; mold[1] = mn1;                                         \
        const float e0 = fexp2(S0[0] - mn0), e1 = fexp2(S0[1] - mn0);         \
        const float e2 = fexp2(S0[2] - mn0), e3 = fexp2(S0[3] - mn0);         \
        lacc[0] = lacc[0] * rs0 + ((e0 + e1) + (e2 + e3));                    \
        *(unsigned*)(smem + pwA) = pk4(e0, e1, e2, e3);                       \
        const float f0 = fexp2(S1[0] - mn1), f1 = fexp2(S1[1] - mn1);         \
        const float f2 = fexp2(S1[2] - mn1), f3 = fexp2(S1[3] - mn1);         \
        lacc[1] = lacc[1] * rs1 + ((f0 + f1) + (f2 + f3));                    \
        *(unsigned*)(smem + pwA + 1024) = pk4(f0, f1, f2, f3);                \
        _Pragma("unroll")                                                     \
        for (int ct = 0; ct < 4; ++ct)                                        \
            _Pragma("unroll")                                                 \
            for (int rr = 0; rr < 4; ++rr) {                                  \
                acc[0][ct][rr] *= rs0;                                        \
                acc[1][ct][rr] *= rs1;                                        \
            }                                                                 \
        asm volatile("s_waitcnt lgkmcnt(0)" ::: "memory");                    \
        barrier_raw();   /* rewritten P visible (uniform: same flags) */      \
    } else {                                                                  \
        lacc[0] += es0; lacc[1] += es1;                                       \
    }                                                                         \
    __builtin_amdgcn_s_setprio(1);                                            \
    _Pragma("unroll")                                                         \
    for (int kki = 0; kki < 2; ++kki) {                                       \
        const int kx = kki << 5;                                              \
        i64 vf_[4], pf_[2];                                                   \
        _Pragma("unroll")                                                     \
        for (int ct = 0; ct < 4; ++ct)                                        \
            vf_[ct] = *(const i64*)(smem + (BASE) + (vA ^ kx) + ct * 1024);   \
        _Pragma("unroll")                                                     \
        for (int qt = 0; qt < 2; ++qt)                                        \
            pf_[qt] = *(const i64*)(smem + (pA ^ kx) + qt * 1024);            \
        _Pragma("unroll")                                                     \
        for (int qt = 0; qt < 2; ++qt)                                        \
            _Pragma("unroll")                                                 \
            for (int ct = 0; ct < 4; ++ct)                                    \
                acc[qt][ct] = __builtin_amdgcn_mfma_f32_16x16x32_fp8_fp8(vf_[ct], pf_[qt], acc[qt][ct], 0, 0, 0); \
    }                                                                         \
    __builtin_amdgcn_s_setprio(0);                                            \
    asm volatile("s_waitcnt lgkmcnt(0)" ::: "memory");                        \
    barrier_raw();   /* B3: buffer BASE free, P rewritable */                 \
    if ((cc) + 2 < nchunks) {                                                 \
        if (t < 256) gl16(kP, smem + (BASE) + kDstOff);                       \
        gl16(vP0, smem + (BASE) + vDstOff0);                                  \
        gl16(vP1, smem + (BASE) + vDstOff1);                                  \
        kP += 4096; vP0 += 64; vP1 += 64;                                     \
        if (w < 4) asm volatile("s_waitcnt vmcnt(3)" ::: "memory");           \
        else       asm volatile("s_waitcnt vmcnt(2)" ::: "memory");           \
        __builtin_amdgcn_sched_barrier(0);                                    \
        barrier_raw();   /* B1: chunk cc+1 landed globally */                 \
    } else if ((cc) + 1 < nchunks) {                                          \
        asm volatile("s_waitcnt vmcnt(0)" ::: "memory");                      \
        __builtin_amdgcn_sched_barrier(0);                                    \
        barrier_raw();                                                        \
    }                                                                         \
} while (0)

__global__ __launch_bounds__(512, 4) void attn(
    const unsigned char* __restrict__ qF,   // [b][n][64] fp8 (log2e-scaled)
    const unsigned char* __restrict__ kF,   // [b][n][64] fp8
    const unsigned char* __restrict__ v2,   // [b][512][n] fp8
    const float* __restrict__ x, const float* __restrict__ gamma,
    float* __restrict__ y, int n)
{
    __shared__ char smem[46336];
    const int b = blockIdx.x >> 1, ch0 = (blockIdx.x & 1) * 256;
    const int i0 = blockIdx.y * 64;
    const int t = threadIdx.x, lane = t & 63, w = t >> 6;
    const int quad = lane >> 4, l16 = lane & 15;
    const int qh = w & 1, g = w >> 1;
    const int sw = (l16 >> 1) & 3;          // read-side swizzle key
    const int boff = (quad & 1) * 8;        // byte-in-part for fragments
    const int phalf = quad >> 1;            // part contribution from quad
    const int p0 = phalf ^ sw;              // kki=0 stored part

    // per-lane invariant LDS byte offsets (kki=1 slice = offset ^ 32)
    const int fA  = (g * 16 + l16) * 64 + p0 * 16 + boff;           // S-phase K frag
    const int vA  = 4096 + (g * 64 + l16) * 64 + p0 * 16 + boff;    // PV V frag (+ct*1024)
    const int pA  = SPOFF + (qh * 32 + l16) * 64 + p0 * 16 + boff;  // PV P frag (+qt*1024)
    const int pwA = SPOFF + (qh * 32 + l16) * 64 + (g ^ sw) * 16 + quad * 4; // P write (+qt*1024)
    const int mxR = SLOFF + qh * 512 + l16 * 16;                    // sMx read (g vector)
    const int mxW = mxR + g * 4;                                    // sMx write (quad0 lanes)

    const unsigned char* Qb = qF + ((size_t)b * n + i0) * RED;
    const unsigned char* Kb = kF + (size_t)b * n * RED;
    const unsigned char* Vb = v2 + ((size_t)b * CH + ch0) * n;

    // staging geometry (source side carries the XOR swizzle; dst is linear)
    const int r = t >> 2, s4 = t & 3, gs = s4 ^ ((r >> 1) & 3);
    const int kDstOff  = t * 16;
    const int vDstOff0 = 4096 + t * 16;
    const int vDstOff1 = 12288 + t * 16;
    const size_t vHalf = (size_t)128 * n;
    const unsigned char* kSrc0 = Kb + (size_t)r * RED + gs * 16;
    const unsigned char* vSrc0 = Vb + (size_t)r * n + gs * 16;

    // ---- prologue: stage Q + chunk 0 (full drain via __syncthreads)
    if (t < 256) {
        gl16(Qb + (size_t)r * RED + gs * 16, smem + SPOFF + kDstOff);
        gl16(kSrc0, smem + kDstOff);
    }
    gl16(vSrc0, smem + vDstOff0);
    gl16(vSrc0 + vHalf, smem + vDstOff1);
    __syncthreads();   // full drain: Q + chunk0 ready (once per kernel)

    // ---- preload Q fragments (B-operand layout: lane=q-col, bytes=red)
    i64 qreg[2][2];
    #pragma unroll
    for (int qt = 0; qt < 2; ++qt) {
        #pragma unroll
        for (int kki = 0; kki < 2; ++kki)
            qreg[qt][kki] = *(const i64*)(smem + ((pA ^ (kki << 5)) + qt * 1024));
    }
    asm volatile("s_waitcnt lgkmcnt(0)" ::: "memory");
    barrier_raw();     // all Q-frag reads done before any P write

    const int nchunks = n >> 6;   // 64 (even) for n=4096
    if (nchunks > 1) {            // chunk 1 in flight across chunk 0
        if (t < 256) gl16(kSrc0 + 4096, smem + STGSZ + kDstOff);
        gl16(vSrc0 + 64, smem + STGSZ + vDstOff0);
        gl16(vSrc0 + vHalf + 64, smem + STGSZ + vDstOff1);
    }
    const unsigned char* kP  = kSrc0 + 8192;
    const unsigned char* vP0 = vSrc0 + 128;
    const unsigned char* vP1 = vSrc0 + vHalf + 128;

    f32x4 acc[2][4];
    const f32x4 zz = {0.f, 0.f, 0.f, 0.f};
    #pragma unroll
    for (int qt = 0; qt < 2; ++qt)
        #pragma unroll
        for (int ct = 0; ct < 4; ++ct) acc[qt][ct] = zz;
    float lacc[2] = {0.f, 0.f};
    float mold[2] = {-3.0e38f, -3.0e38f};

    for (int c = 0; c < nchunks; c += 2) {
        CHUNK(0, c);
        CHUNK(STGSZ, c + 1);
    }

    // ---- l reduction: over quads (shfl), then over the 4 g-waves (LDS)
    float* sL = (float*)(smem + SLOFF);   // [8 waves][32] (aliases sMx; safe post-loop)
    #pragma unroll
    for (int qt = 0; qt < 2; ++qt) {
        float v = lacc[qt];
        v += __shfl_xor(v, 16);
        v += __shfl_xor(v, 32);
        lacc[qt] = v;
    }
    __syncthreads();   // all in-loop sMx/flag reads done before sL overwrite
    if (quad == 0) {
        #pragma unroll
        for (int qt = 0; qt < 2; ++qt) sL[w * 32 + qt * 16 + l16] = lacc[qt];
    }
    __syncthreads();
    float il[2];
    #pragma unroll
    for (int qt = 0; qt < 2; ++qt) {
        const int idx = qt * 16 + l16;
        il[qt] = 1.0f / (sL[qh * 32 + idx] + sL[(2 + qh) * 32 + idx] +
                         sL[(4 + qh) * 32 + idx] + sL[(6 + qh) * 32 + idx]);
    }

    // ---- epilogue: 4 rounds of 64 channels; transpose via LDS, y = g*(O/l)+x
    const float gm = gamma[0];
    float* sT = (float*)smem;   // [64][68] f32 = 17.4 KB (aliases buf0)
    #pragma unroll
    for (int cr = 0; cr < 4; ++cr) {
        __syncthreads();
        if (g == cr) {
            #pragma unroll
            for (int ct = 0; ct < 4; ++ct)
                #pragma unroll
                for (int qt = 0; qt < 2; ++qt)
                    #pragma unroll
                    for (int rr = 0; rr < 4; ++rr)
                        sT[(ct * 16 + quad * 4 + rr) * 68 + qh * 32 + qt * 16 + l16] =
                            acc[qt][ct][rr] * il[qt];
        }
        __syncthreads();
        const int row = t >> 3, seg = (t & 7) * 8;
        const size_t gb = ((size_t)b * CH + ch0 + cr * 64 + row) * n + i0 + seg;
        #pragma unroll
        for (int u = 0; u < 2; ++u) {
            const float4 xv = *(const float4*)&x[gb + u * 4];
            const float* op = &sT[row * 68 + seg + u * 4];
            float4 yv;
            yv.x = gm * op[0] + xv.x;
            yv.y = gm * op[1] + xv.y;
            yv.z = gm * op[2] + xv.z;
            yv.w = gm * op[3] + xv.w;
            *(float4*)&y[gb + u * 4] = yv;
        }
    }
}

// ---------------------------------------------------------------------------
extern "C" void kernel_launch(void* const* d_in, const int* in_sizes, int n_in,
                              void* d_out, int out_size, void* d_ws, size_t ws_size,
                              hipStream_t stream) {
    const float* x     = (const float*)d_in[0];
    const float* Wq    = (const float*)d_in[1];
    const float* bq    = (const float*)d_in[2];
    const float* Wk    = (const float*)d_in[3];
    const float* bk    = (const float*)d_in[4];
    const float* Wv    = (const float*)d_in[5];
    const float* bv    = (const float*)d_in[6];
    const float* gamma = (const float*)d_in[7];
    float* y = (float*)d_out;

    const int N = 64 * 64;
    const int B = in_sizes[0] / (CH * N);   // = 4

    char* ws = (char*)d_ws;
    unsigned char* xT   = (unsigned char*)ws;  ws += (size_t)B * N * CH;
    unsigned char* qF   = (unsigned char*)ws;  ws += (size_t)B * N * RED;
    unsigned char* kF   = (unsigned char*)ws;  ws += (size_t)B * N * RED;
    unsigned char* v2   = (unsigned char*)ws;  ws += (size_t)B * CH * N;
    unsigned char* Wcat = (unsigned char*)ws;

    prep_w<<<dim3(640), 128, 0, stream>>>(Wq, Wk, Wv, Wcat);
    cast_xt<<<dim3(N / 64, CH / 64, B), 256, 0, stream>>>(x, xT, N);
    qkv_gemm<<<dim3(N / 128, 5, B), 256, 0, stream>>>(xT, Wcat, bq, bk, bv, qF, kF, v2, N);
    attn<<<dim3(2 * B, N / 64), 512, 0, stream>>>(qF, kF, v2, x, gamma, y, N);
}

// Round 7
// 222.732 us; speedup vs baseline: 1.0861x; 1.0861x over previous
//
#include <hip/hip_runtime.h>
#include <math.h>

#define CH 512
#define RED 64

typedef __attribute__((ext_vector_type(4))) float f32x4;
typedef long i64;

typedef const __attribute__((address_space(1))) void* gas_t;
typedef __attribute__((address_space(3))) void* las_t;

static __device__ __forceinline__ void gl16(const void* g, void* l) {
    __builtin_amdgcn_global_load_lds((gas_t)g, (las_t)l, 16, 0, 0);
}

// pack f32 -> fp8 e4m3
static __device__ __forceinline__ unsigned pk4(float a, float b, float c, float d) {
    int w = __builtin_amdgcn_cvt_pk_fp8_f32(a, b, 0, false);
    w = __builtin_amdgcn_cvt_pk_fp8_f32(c, d, w, true);
    return (unsigned)w;
}
static __device__ __forceinline__ unsigned char pk1(float a) {
    return (unsigned char)(__builtin_amdgcn_cvt_pk_fp8_f32(a, a, 0, false) & 0xFF);
}

// hardware exp2 (v_exp_f32 IS base-2)
static __device__ __forceinline__ float fexp2(float v) {
#if __has_builtin(__builtin_amdgcn_exp2f)
    return __builtin_amdgcn_exp2f(v);
#else
    float r; asm("v_exp_f32 %0, %1" : "=v"(r) : "v"(v)); return r;
#endif
}

// raw workgroup barrier with compiler memory fences (no implicit vmcnt(0) drain)
static __device__ __forceinline__ void barrier_raw() {
    asm volatile("" ::: "memory");
    __builtin_amdgcn_s_barrier();
    asm volatile("" ::: "memory");
}

// ---------------------------------------------------------------------------
// prep_w: Wq|Wk|Wv f32 -> Wcat fp8 [640][512]; rows 0-63 q, 64-127 k, 128-639 v.
// ---------------------------------------------------------------------------
__global__ __launch_bounds__(128) void prep_w(
    const float* __restrict__ Wq, const float* __restrict__ Wk,
    const float* __restrict__ Wv, unsigned char* __restrict__ Wcat)
{
    const int r = blockIdx.x, t = threadIdx.x;
    const float* src = (r < 64) ? (Wq + (size_t)r * CH)
                     : (r < 128) ? (Wk + (size_t)(r - 64) * CH)
                                 : (Wv + (size_t)(r - 128) * CH);
    const float4 v = *(const float4*)&src[t * 4];
    *(unsigned*)&Wcat[(size_t)r * CH + t * 4] = pk4(v.x, v.y, v.z, v.w);
}

// ---------------------------------------------------------------------------
// cast_xt: x f32 [b][c][n] -> xT fp8 [b][n][512].  64x64 tiles.
// ---------------------------------------------------------------------------
__global__ __launch_bounds__(256) void cast_xt(
    const float* __restrict__ x, unsigned char* __restrict__ xT, int n)
{
    __shared__ float sX[64][65];
    const int b = blockIdx.z, i0 = blockIdx.x * 64, c0 = blockIdx.y * 64;
    const int t = threadIdx.x;
    #pragma unroll
    for (int s = 0; s < 4; ++s) {
        const int id = s * 256 + t, c = id >> 4, seg = id & 15;
        *(float4*)&sX[c][seg * 4] = *(const float4*)&x[((size_t)b * CH + c0 + c) * n + i0 + seg * 4];
    }
    __syncthreads();
    const int i = t >> 2, cp = t & 3;
    uint4 w;
    w.x = pk4(sX[cp*16+ 0][i], sX[cp*16+ 1][i], sX[cp*16+ 2][i], sX[cp*16+ 3][i]);
    w.y = pk4(sX[cp*16+ 4][i], sX[cp*16+ 5][i], sX[cp*16+ 6][i], sX[cp*16+ 7][i]);
    w.z = pk4(sX[cp*16+ 8][i], sX[cp*16+ 9][i], sX[cp*16+10][i], sX[cp*16+11][i]);
    w.w = pk4(sX[cp*16+12][i], sX[cp*16+13][i], sX[cp*16+14][i], sX[cp*16+15][i]);
    *(uint4*)&xT[((size_t)b * n + i0 + i) * CH + c0 + cp * 16] = w;
}

// ---------------------------------------------------------------------------
// qkv_gemm v2 (fp8): out = xT * Wcat^T + bias.  128i x 128o tiles, K=512.
// DOUBLE-BUFFERED staging with counted vmcnt (attn-v4 recipe): stage(c+1)
// in flight across MFMA(c); no vmcnt(0) drain in the steady-state loop.
// q-rows scaled by log2(e) before fp8 quantization (attn exp2 fold).
// LDS 2 x 20KB.  5 gl16/thread/chunk -> vmcnt(5) waits exactly chunk c+1.
// ---------------------------------------------------------------------------
__global__ __launch_bounds__(256, 4) void qkv_gemm(
    const unsigned char* __restrict__ xT, const unsigned char* __restrict__ Wcat,
    const float* __restrict__ bq, const float* __restrict__ bk,
    const float* __restrict__ bv,
    unsigned char* __restrict__ qF, unsigned char* __restrict__ kF,
    unsigned char* __restrict__ v2, int n)
{
    __shared__ char smem[40960];   // 2 x (sA 128x80 | sB 128x80)
    const int b = blockIdx.z, i0 = blockIdx.x * 128, o0 = blockIdx.y * 128;
    const int t = threadIdx.x, lane = t & 63;
    const int quad = lane >> 4, l16 = lane & 15;
    const int wrow = (t >> 6) & 1, wcol = t >> 7;

    f32x4 acc[4][4];
    const f32x4 zz = {0.f, 0.f, 0.f, 0.f};
    #pragma unroll
    for (int mi = 0; mi < 4; ++mi)
        #pragma unroll
        for (int ci = 0; ci < 4; ++ci) acc[mi][ci] = zz;

    const unsigned char* Ab = xT + ((size_t)b * n + i0) * CH;
    const unsigned char* Bb = Wcat + (size_t)o0 * CH;

    // staging of one 64-c chunk into buffer dst (5 gl16 per thread)
    auto stageChunk = [&](int c0, char* dst) {
        #pragma unroll
        for (int s = 0; s < 5; ++s) {
            const int c = s * 256 + t;
            const bool isA = c < 640;
            const int tc = isA ? c : c - 640;
            const int r = tc / 5, p = (tc % 5) & 3;
            gl16((isA ? Ab : Bb) + (size_t)r * CH + c0 + p * 16,
                 dst + (isA ? 0 : 10240) + (size_t)tc * 16);
        }
    };

    stageChunk(0, smem);
    __syncthreads();                    // full drain once (chunk 0 ready)
    stageChunk(64, smem + 20480);       // chunk 1 in flight across chunk 0

    #pragma unroll
    for (int ci = 0; ci < 8; ++ci) {
        char* cb = smem + (ci & 1) * 20480;
        #pragma unroll
        for (int kk = 0; kk < 64; kk += 32) {
            i64 af[4], bf[4];
            #pragma unroll
            for (int mi = 0; mi < 4; ++mi)
                af[mi] = *(const i64*)(cb + (wrow * 64 + mi * 16 + l16) * 80 + kk + quad * 8);
            #pragma unroll
            for (int cj = 0; cj < 4; ++cj)
                bf[cj] = *(const i64*)(cb + 10240 + (wcol * 64 + cj * 16 + l16) * 80 + kk + quad * 8);
            __builtin_amdgcn_s_setprio(1);
            #pragma unroll
            for (int mi = 0; mi < 4; ++mi)
                #pragma unroll
                for (int cj = 0; cj < 4; ++cj)
                    acc[mi][cj] = __builtin_amdgcn_mfma_f32_16x16x32_fp8_fp8(af[mi], bf[cj], acc[mi][cj], 0, 0, 0);
            __builtin_amdgcn_s_setprio(0);
        }
        asm volatile("s_waitcnt lgkmcnt(0)" ::: "memory");
        barrier_raw();                  // all reads of cb done -> cb free
        if (ci + 2 < 8) {
            stageChunk((ci + 2) * 64, cb);   // refill the buffer just freed
            asm volatile("s_waitcnt vmcnt(5)" ::: "memory");  // chunk ci+1 landed
            __builtin_amdgcn_sched_barrier(0);
            barrier_raw();
        } else if (ci + 1 < 8) {
            asm volatile("s_waitcnt vmcnt(0)" ::: "memory");  // tail: drain chunk 7
            __builtin_amdgcn_sched_barrier(0);
            barrier_raw();
        }
    }

    float bb[4], scl[4];
    #pragma unroll
    for (int ci = 0; ci < 4; ++ci) {
        const int o = wcol * 64 + ci * 16 + l16;
        if (o0 == 0) {
            bb[ci]  = (o < 64) ? bq[o] : bk[o - 64];
            scl[ci] = (o < 64) ? 1.44269504088896f : 1.0f;
        } else {
            bb[ci]  = bv[o0 - 128 + o];
            scl[ci] = 1.0f;
        }
    }
    __syncthreads();
    unsigned char* sE = (unsigned char*)smem;    // 128 x 144
    if (o0 == 0) {
        #pragma unroll
        for (int mi = 0; mi < 4; ++mi)
            #pragma unroll
            for (int ci = 0; ci < 4; ++ci)
                #pragma unroll
                for (int r = 0; r < 4; ++r)
                    sE[(wrow*64 + mi*16 + quad*4 + r) * 144 + wcol*64 + ci*16 + l16] =
                        pk1((acc[mi][ci][r] + bb[ci]) * scl[ci]);
    } else {
        #pragma unroll
        for (int mi = 0; mi < 4; ++mi)
            #pragma unroll
            for (int ci = 0; ci < 4; ++ci)
                #pragma unroll
                for (int r = 0; r < 4; ++r)
                    sE[(wcol*64 + ci*16 + l16) * 144 + wrow*64 + mi*16 + quad*4 + r] =
                        pk1(acc[mi][ci][r] + bb[ci]);
    }
    __syncthreads();
    if (o0 == 0) {
        #pragma unroll
        for (int u = 0; u < 2; ++u) {
            const int id = u * 256 + t, i = id >> 2, p = id & 3;
            *(uint4*)&qF[((size_t)b * n + i0 + i) * RED + p * 16] = *(const uint4*)&sE[i * 144 + p * 16];
        }
        #pragma unroll
        for (int u = 0; u < 2; ++u) {
            const int id = u * 256 + t, i = id >> 2, p = id & 3;
            *(uint4*)&kF[((size_t)b * n + i0 + i) * RED + p * 16] = *(const uint4*)&sE[i * 144 + 64 + p * 16];
        }
    } else {
        #pragma unroll
        for (int u = 0; u < 4; ++u) {
            const int id = u * 256 + t, o = id >> 3, p = id & 7;
            *(uint4*)&v2[((size_t)b * CH + (o0 - 128) + o) * n + i0 + p * 16] =
                *(const uint4*)&sE[o * 144 + p * 16];
        }
    }
}

// ---------------------------------------------------------------------------
// rowmax: m_i = max_j S' (bit-identical S' to attn's fp8 MFMA; qF already
// carries the log2e scale so the stored max is in the exp2 domain).
// ---------------------------------------------------------------------------
__global__ __launch_bounds__(256, 4) void rowmax(
    const unsigned char* __restrict__ qF, const unsigned char* __restrict__ kF,
    unsigned* __restrict__ mKey, int n)
{
    __shared__ char smem[20480];
    const int b = blockIdx.z, i0 = blockIdx.y * 128, j0 = blockIdx.x * 128;
    const int t = threadIdx.x, lane = t & 63;
    const int quad = lane >> 4, l16 = lane & 15;
    const int wrow = (t >> 6) & 1, wcol = t >> 7;

    const unsigned char* Qb = qF + ((size_t)b * n + i0) * RED;
    const unsigned char* Kb = kF + ((size_t)b * n + j0) * RED;
    #pragma unroll
    for (int s = 0; s < 5; ++s) {
        const int c = s * 256 + t;
        const bool isQ = c < 640;
        const int tc = isQ ? c : c - 640;
        const int r = tc / 5, p = (tc % 5) & 3;
        gl16((isQ ? Qb : Kb) + (size_t)r * RED + p * 16,
             smem + (isQ ? 0 : 10240) + (size_t)tc * 16);
    }
    __syncthreads();

    f32x4 acc[4][4];
    const f32x4 zz = {0.f, 0.f, 0.f, 0.f};
    #pragma unroll
    for (int mi = 0; mi < 4; ++mi)
        #pragma unroll
        for (int ci = 0; ci < 4; ++ci) acc[mi][ci] = zz;

    #pragma unroll
    for (int kk = 0; kk < 64; kk += 32) {
        i64 af[4], bf[4];
        #pragma unroll
        for (int mi = 0; mi < 4; ++mi)
            af[mi] = *(const i64*)(smem + (wrow * 64 + mi * 16 + l16) * 80 + kk + quad * 8);
        #pragma unroll
        for (int ci = 0; ci < 4; ++ci)
            bf[ci] = *(const i64*)(smem + 10240 + (wcol * 64 + ci * 16 + l16) * 80 + kk + quad * 8);
        #pragma unroll
        for (int mi = 0; mi < 4; ++mi)
            #pragma unroll
            for (int ci = 0; ci < 4; ++ci)
                acc[mi][ci] = __builtin_amdgcn_mfma_f32_16x16x32_fp8_fp8(af[mi], bf[ci], acc[mi][ci], 0, 0, 0);
    }

    #pragma unroll
    for (int mi = 0; mi < 4; ++mi)
        #pragma unroll
        for (int r = 0; r < 4; ++r) {
            float mx = fmaxf(fmaxf(acc[mi][0][r], acc[mi][1][r]),
                             fmaxf(acc[mi][2][r], acc[mi][3][r]));
            #pragma unroll
            for (int off = 1; off < 16; off <<= 1) mx = fmaxf(mx, __shfl_xor(mx, off));
            if (l16 == 0) {
                union { float f; unsigned u; } cv; cv.f = mx;
                const unsigned key = ((int)cv.u >= 0) ? (cv.u + 0x80000000u) : ~cv.u;
                atomicMax(&mKey[(size_t)b * n + i0 + wrow * 64 + mi * 16 + quad * 4 + r], key);
            }
        }
}

// ---------------------------------------------------------------------------
// attn v4 (reverted to R2's proven version): 64q x 256ch, counted-vmcnt
// 3-barrier pipeline, precomputed row-max via mKey, exp2-domain softmax.
// LDS 45 KB, __launch_bounds__(512,4) -> 2 blocks/CU, 16 waves/CU.
// ---------------------------------------------------------------------------
#define STGSZ 20480
#define SPOFF 40960
#define SLOFF 45056

__global__ __launch_bounds__(512, 4) void attn(
    const unsigned char* __restrict__ qF,   // [b][n][64] fp8 (log2e-scaled)
    const unsigned char* __restrict__ kF,   // [b][n][64] fp8
    const unsigned char* __restrict__ v2,   // [b][512][n] fp8
    const unsigned* __restrict__ mKey,
    const float* __restrict__ x, const float* __restrict__ gamma,
    float* __restrict__ y, int n)
{
    __shared__ char smem[46080];
    const int b = blockIdx.x >> 1, ch0 = (blockIdx.x & 1) * 256;
    const int i0 = blockIdx.y * 64;
    const int t = threadIdx.x, lane = t & 63, w = t >> 6;
    const int quad = lane >> 4, l16 = lane & 15;
    const int qh = w & 1, g = w >> 1;
    const int sw = (l16 >> 1) & 3;          // read-side swizzle key
    const int boff = (quad & 1) * 8;        // byte-in-part for fragments
    const int phalf = quad >> 1;            // part contribution from quad

    const unsigned char* Qb = qF + ((size_t)b * n + i0) * RED;
    const unsigned char* Kb = kF + (size_t)b * n * RED;
    const unsigned char* Vb = v2 + ((size_t)b * CH + ch0) * n;

    // staging of one 64-j chunk: K (4KB, waves 0-3: 1 gl16/thread) +
    // V (16KB, all waves: 2 gl16/thread).  Per-wave vmcnt cost: w<4 -> 3, else 2.
    auto stage = [&](int jn, char* dst) {
        const int r = t >> 2, s4 = t & 3, gs = s4 ^ ((r >> 1) & 3);
        if (t < 256)
            gl16(Kb + (size_t)(jn + r) * RED + gs * 16, dst + (size_t)t * 16);
        #pragma unroll
        for (int ps = 0; ps < 2; ++ps) {
            const int id = ps * 512 + t, vr = id >> 2, vs = id & 3;
            const int vgs = vs ^ ((vr >> 1) & 3);
            gl16(Vb + (size_t)vr * n + jn + vgs * 16, dst + 4096 + (size_t)id * 16);
        }
    };

    // ---- prologue: stage Q + chunk 0; load mrow early
    {
        const int r = t >> 2, s4 = t & 3, gs = s4 ^ ((r >> 1) & 3);
        if (t < 256)
            gl16(Qb + (size_t)r * RED + gs * 16, smem + SPOFF + (size_t)t * 16);
        stage(0, smem);
    }
    float mrow[2];
    #pragma unroll
    for (int qt = 0; qt < 2; ++qt) {
        const unsigned u = mKey[(size_t)b * n + i0 + qh * 32 + qt * 16 + l16];
        const unsigned bits = (u >= 0x80000000u) ? (u - 0x80000000u) : ~u;
        union { unsigned u; float f; } cv; cv.u = bits;
        mrow[qt] = cv.f;
    }
    __syncthreads();   // full drain: Q + chunk0 ready (once per kernel)

    // ---- preload Q fragments (B-operand layout: lane=q-col, bytes=red)
    i64 qreg[2][2];
    #pragma unroll
    for (int qt = 0; qt < 2; ++qt) {
        const int row = qh * 32 + qt * 16 + l16;
        #pragma unroll
        for (int kki = 0; kki < 2; ++kki) {
            const int p = (kki * 2 + phalf) ^ sw;
            qreg[qt][kki] = *(const i64*)(smem + SPOFF + row * 64 + p * 16 + boff);
        }
    }
    asm volatile("s_waitcnt lgkmcnt(0)" ::: "memory");
    barrier_raw();     // all Q-frag reads done before any P write

    const int nchunks = n >> 6;
    if (nchunks > 1) stage(64, smem + STGSZ);   // chunk 1 in flight across chunk 0

    f32x4 acc[2][4];
    const f32x4 zz = {0.f, 0.f, 0.f, 0.f};
    #pragma unroll
    for (int qt = 0; qt < 2; ++qt)
        #pragma unroll
        for (int ct = 0; ct < 4; ++ct) acc[qt][ct] = zz;
    float lacc[2] = {0.f, 0.f};

    for (int c = 0; c < nchunks; ++c) {
        char* cur = smem + (c & 1) * STGSZ;

        // ---- S^T = K.Q^T : wave (qh,g) -> j-tile g, q-tiles qh*2..+1
        f32x4 S[2];
        S[0] = zz; S[1] = zz;
        __builtin_amdgcn_s_setprio(1);
        #pragma unroll
        for (int kki = 0; kki < 2; ++kki) {
            const int p = (kki * 2 + phalf) ^ sw;
            const i64 kf = *(const i64*)(cur + (g * 16 + l16) * 64 + p * 16 + boff);
            #pragma unroll
            for (int qt = 0; qt < 2; ++qt)
                S[qt] = __builtin_amdgcn_mfma_f32_16x16x32_fp8_fp8(kf, qreg[qt][kki], S[qt], 0, 0, 0);
        }
        __builtin_amdgcn_s_setprio(0);
        // ---- P = exp2(S' - m'): lane holds q-col l16, j-rows quad*4+r -> packed b32
        #pragma unroll
        for (int qt = 0; qt < 2; ++qt) {
            const float e0 = fexp2(S[qt][0] - mrow[qt]);
            const float e1 = fexp2(S[qt][1] - mrow[qt]);
            const float e2 = fexp2(S[qt][2] - mrow[qt]);
            const float e3 = fexp2(S[qt][3] - mrow[qt]);
            lacc[qt] += (e0 + e1) + (e2 + e3);
            const int qrow = qh * 32 + qt * 16 + l16;
            const int pp = g ^ sw;
            *(unsigned*)(smem + SPOFF + qrow * 64 + pp * 16 + quad * 4) = pk4(e0, e1, e2, e3);
        }
        asm volatile("s_waitcnt lgkmcnt(0)" ::: "memory");
        barrier_raw();   // B2: P visible to all waves; chunk c+1 staging STILL in flight

        // ---- PV: O^T tiles, A = V rows (ch), B = P rows (q)
        __builtin_amdgcn_s_setprio(1);
        #pragma unroll
        for (int kki = 0; kki < 2; ++kki) {
            const int p = (kki * 2 + phalf) ^ sw;
            i64 vf[4], pf[2];
            #pragma unroll
            for (int ct = 0; ct < 4; ++ct) {
                const int row = g * 64 + ct * 16 + l16;
                vf[ct] = *(const i64*)(cur + 4096 + row * 64 + p * 16 + boff);
            }
            #pragma unroll
            for (int qt = 0; qt < 2; ++qt) {
                const int qrow = qh * 32 + qt * 16 + l16;
                pf[qt] = *(const i64*)(smem + SPOFF + qrow * 64 + p * 16 + boff);
            }
            #pragma unroll
            for (int qt = 0; qt < 2; ++qt)
                #pragma unroll
                for (int ct = 0; ct < 4; ++ct)
                    acc[qt][ct] = __builtin_amdgcn_mfma_f32_16x16x32_fp8_fp8(vf[ct], pf[qt], acc[qt][ct], 0, 0, 0);
        }
        __builtin_amdgcn_s_setprio(0);

        asm volatile("s_waitcnt lgkmcnt(0)" ::: "memory");
        barrier_raw();   // all reads of cur + P done -> cur buffer free, P rewritable

        if (c + 2 < nchunks) {
            stage((c + 2) << 6, cur);           // refill the buffer just freed
            // wait for chunk c+1 (leave own c+2 loads in flight)
            if (w < 4) asm volatile("s_waitcnt vmcnt(3)" ::: "memory");
            else       asm volatile("s_waitcnt vmcnt(2)" ::: "memory");
            __builtin_amdgcn_sched_barrier(0);
            barrier_raw();                      // chunk c+1 landed globally
        } else if (c + 1 < nchunks) {
            asm volatile("s_waitcnt vmcnt(0)" ::: "memory");
            __builtin_amdgcn_sched_barrier(0);
            barrier_raw();                      // tail: drain chunk c+1
        }
    }

    // ---- l reduction: over quads (shfl), then over the 4 g-waves (LDS)
    float* sL = (float*)(smem + SLOFF);   // [8 waves][32]
    #pragma unroll
    for (int qt = 0; qt < 2; ++qt) {
        float v = lacc[qt];
        v += __shfl_xor(v, 16);
        v += __shfl_xor(v, 32);
        lacc[qt] = v;
    }
    if (quad == 0) {
        #pragma unroll
        for (int qt = 0; qt < 2; ++qt) sL[w * 32 + qt * 16 + l16] = lacc[qt];
    }
    __syncthreads();
    float il[2];
    #pragma unroll
    for (int qt = 0; qt < 2; ++qt) {
        const int idx = qt * 16 + l16;
        il[qt] = 1.0f / (sL[qh * 32 + idx] + sL[(2 + qh) * 32 + idx] +
                         sL[(4 + qh) * 32 + idx] + sL[(6 + qh) * 32 + idx]);
    }

    // ---- epilogue: 4 rounds of 64 channels; transpose via LDS, y = g*(O/l)+x
    const float gm = gamma[0];
    float* sT = (float*)smem;   // [64][68] f32 = 17.4 KB (aliases buf0)
    #pragma unroll
    for (int cr = 0; cr < 4; ++cr) {
        __syncthreads();
        if (g == cr) {
            #pragma unroll
            for (int ct = 0; ct < 4; ++ct)
                #pragma unroll
                for (int qt = 0; qt < 2; ++qt)
                    #pragma unroll
                    for (int rr = 0; rr < 4; ++rr)
                        sT[(ct * 16 + quad * 4 + rr) * 68 + qh * 32 + qt * 16 + l16] =
                            acc[qt][ct][rr] * il[qt];
        }
        __syncthreads();
        const int row = t >> 3, seg = (t & 7) * 8;
        const size_t gb = ((size_t)b * CH + ch0 + cr * 64 + row) * n + i0 + seg;
        #pragma unroll
        for (int u = 0; u < 2; ++u) {
            const float4 xv = *(const float4*)&x[gb + u * 4];
            const float* op = &sT[row * 68 + seg + u * 4];
            float4 yv;
            yv.x = gm * op[0] + xv.x;
            yv.y = gm * op[1] + xv.y;
            yv.z = gm * op[2] + xv.z;
            yv.w = gm * op[3] + xv.w;
            *(float4*)&y[gb + u * 4] = yv;
        }
    }
}

// ---------------------------------------------------------------------------
extern "C" void kernel_launch(void* const* d_in, const int* in_sizes, int n_in,
                              void* d_out, int out_size, void* d_ws, size_t ws_size,
                              hipStream_t stream) {
    const float* x     = (const float*)d_in[0];
    const float* Wq    = (const float*)d_in[1];
    const float* bq    = (const float*)d_in[2];
    const float* Wk    = (const float*)d_in[3];
    const float* bk    = (const float*)d_in[4];
    const float* Wv    = (const float*)d_in[5];
    const float* bv    = (const float*)d_in[6];
    const float* gamma = (const float*)d_in[7];
    float* y = (float*)d_out;

    const int N = 64 * 64;
    const int B = in_sizes[0] / (CH * N);   // = 4

    char* ws = (char*)d_ws;
    unsigned char* xT   = (unsigned char*)ws;  ws += (size_t)B * N * CH;
    unsigned char* qF   = (unsigned char*)ws;  ws += (size_t)B * N * RED;
    unsigned char* kF   = (unsigned char*)ws;  ws += (size_t)B * N * RED;
    unsigned char* v2   = (unsigned char*)ws;  ws += (size_t)B * CH * N;
    unsigned char* Wcat = (unsigned char*)ws;  ws += (size_t)640 * CH;
    unsigned* mKey      = (unsigned*)ws;

    hipMemsetAsync(mKey, 0, (size_t)B * N * 4, stream);

    prep_w<<<dim3(640), 128, 0, stream>>>(Wq, Wk, Wv, Wcat);
    cast_xt<<<dim3(N / 64, CH / 64, B), 256, 0, stream>>>(x, xT, N);
    qkv_gemm<<<dim3(N / 128, 5, B), 256, 0, stream>>>(xT, Wcat, bq, bk, bv, qF, kF, v2, N);
    rowmax<<<dim3(N / 128, N / 128, B), 256, 0, stream>>>(qF, kF, mKey, N);
    attn<<<dim3(4 * B / 2, N / 64), 512, 0, stream>>>(qF, kF, v2, mKey, x, gamma, y, N);
}